// Round 1
// baseline (204.783 us; speedup 1.0000x reference)
//
#include <hip/hip_runtime.h>
#include <hip/hip_bf16.h>
#include <math.h>

#define Bn 32
#define Ln 512
#define Hn 1024
#define Qn 128

typedef __bf16 bf16x8 __attribute__((ext_vector_type(8)));
typedef float f32x4 __attribute__((ext_vector_type(4)));

__device__ __forceinline__ unsigned short f2bf(float x) {
    union { float f; unsigned int u; } v; v.f = x;
    unsigned int r = v.u + 0x7fffu + ((v.u >> 16) & 1u);  // round-to-nearest-even
    return (unsigned short)(r >> 16);
}
__device__ __forceinline__ float bf2f(unsigned short h) {
    union { unsigned int u; float f; } v; v.u = ((unsigned int)h) << 16;
    return v.f;
}

// ---------------------------------------------------------------------------
// Kernel 1: span pooling -> h_pair (4096 x 3072) bf16
// one block per (b,q) pair; 256 threads, 4 hidden dims each (float4)
// ---------------------------------------------------------------------------
__global__ __launch_bounds__(256) void pool_kernel(const float* __restrict__ hs,
                                                   const int* __restrict__ spans,
                                                   unsigned short* __restrict__ hp) {
    const int pair = blockIdx.x;          // b*Q + q
    const int b = pair >> 7;              // Q = 128
    const int tid = threadIdx.x;

    // dtype probe: int64 spans -> second 32-bit word is the high half of
    // asp_s[0] (== 0); int32 spans -> it's asp_e[0] which is always >= 2.
    const bool is64 = (spans[1] == 0);
    int s_a, e_a, s_o, e_o;
    if (is64) {
        s_a = spans[(pair * 4 + 0) * 2]; e_a = spans[(pair * 4 + 1) * 2];
        s_o = spans[(pair * 4 + 2) * 2]; e_o = spans[(pair * 4 + 3) * 2];
    } else {
        s_a = spans[pair * 4 + 0]; e_a = spans[pair * 4 + 1];
        s_o = spans[pair * 4 + 2]; e_o = spans[pair * 4 + 3];
    }

    const float4* base = (const float4*)hs + (size_t)b * Ln * (Hn / 4);

    float4 A, O;
    if (s_a >= 2 && e_a >= s_a) {
        float sx = 0.f, sy = 0.f, sz = 0.f, sw = 0.f;
        for (int t = s_a; t <= e_a; ++t) {
            float4 v = base[t * (Hn / 4) + tid];
            sx += v.x; sy += v.y; sz += v.z; sw += v.w;
        }
        float inv = 1.0f / (float)(e_a - s_a + 1);
        A.x = sx * inv; A.y = sy * inv; A.z = sz * inv; A.w = sw * inv;
    } else {
        A = base[(Hn / 4) + tid];         // sep token, row 1
    }
    if (s_o >= 2 && e_o >= s_o) {
        float sx = 0.f, sy = 0.f, sz = 0.f, sw = 0.f;
        for (int t = s_o; t <= e_o; ++t) {
            float4 v = base[t * (Hn / 4) + tid];
            sx += v.x; sy += v.y; sz += v.z; sw += v.w;
        }
        float inv = 1.0f / (float)(e_o - s_o + 1);
        O.x = sx * inv; O.y = sy * inv; O.z = sz * inv; O.w = sw * inv;
    } else {
        O = base[(Hn / 4) + tid];
    }

    unsigned short* row = hp + (size_t)pair * 3072;
    const int d = tid * 4;
    ushort4 pa, po, pp;
    pa.x = f2bf(A.x); pa.y = f2bf(A.y); pa.z = f2bf(A.z); pa.w = f2bf(A.w);
    po.x = f2bf(O.x); po.y = f2bf(O.y); po.z = f2bf(O.z); po.w = f2bf(O.w);
    pp.x = f2bf(A.x * O.x); pp.y = f2bf(A.y * O.y);
    pp.z = f2bf(A.z * O.z); pp.w = f2bf(A.w * O.w);
    *(ushort4*)(row + d) = pa;
    *(ushort4*)(row + 1024 + d) = po;
    *(ushort4*)(row + 2048 + d) = pp;
}

// ---------------------------------------------------------------------------
// Kernel 2: convert W1 (256x3072) and W2 (128x256) fp32 -> bf16
// ---------------------------------------------------------------------------
__global__ __launch_bounds__(256) void convert_w(const float* __restrict__ W1,
                                                 const float* __restrict__ W2,
                                                 unsigned short* __restrict__ w1b,
                                                 unsigned short* __restrict__ w2b) {
    const int n1 = 256 * 3072;
    const int n2 = 128 * 256;
    for (int i = blockIdx.x * blockDim.x + threadIdx.x; i < n1 + n2;
         i += gridDim.x * blockDim.x) {
        if (i < n1) w1b[i] = f2bf(W1[i]);
        else        w2b[i - n1] = f2bf(W2[i - n1]);
    }
}

// ---------------------------------------------------------------------------
// Kernel 3/4: C = gelu(A @ Bw^T + bias), bf16 in/out, fp32 accum.
// A: M x K row-major, Bw: N x K row-major (i.e. B^T layout), C: M x N bf16.
// 64x64 tile per block, 256 threads = 4 waves in 2x2, each wave 32x32
// via 2x2 mfma_f32_16x16x32_bf16. M,N,K all multiples of 64.
// ---------------------------------------------------------------------------
__global__ __launch_bounds__(256) void gemm_bt_gelu(const unsigned short* __restrict__ A,
                                                    const unsigned short* __restrict__ Bw,
                                                    const float* __restrict__ bias,
                                                    unsigned short* __restrict__ C,
                                                    int M, int N, int K) {
    __shared__ __align__(16) unsigned short As[64][72];  // +8 pad: 144B stride, 16B aligned
    __shared__ __align__(16) unsigned short Bs[64][72];

    const int tid = threadIdx.x;
    const int lane = tid & 63;
    const int wid = tid >> 6;
    const int wM = (wid >> 1) * 32;
    const int wN = (wid & 1) * 32;
    const int quad = lane >> 4;
    const int l16 = lane & 15;
    const int m0 = blockIdx.x * 64;
    const int n0 = blockIdx.y * 64;
    const int lr = tid >> 3;          // 0..31
    const int lc = (tid & 7) * 8;     // 0..56 step 8

    f32x4 acc[2][2] = {};

    for (int k0 = 0; k0 < K; k0 += 64) {
#pragma unroll
        for (int i = 0; i < 2; ++i) {
            const int r = lr + i * 32;
            uint4 av = *(const uint4*)(A + (size_t)(m0 + r) * K + k0 + lc);
            *(uint4*)(&As[r][lc]) = av;
            uint4 bv = *(const uint4*)(Bw + (size_t)(n0 + r) * K + k0 + lc);
            *(uint4*)(&Bs[r][lc]) = bv;
        }
        __syncthreads();
#pragma unroll
        for (int kk = 0; kk < 64; kk += 32) {
            bf16x8 a0 = *(const bf16x8*)&As[wM + l16][kk + quad * 8];
            bf16x8 a1 = *(const bf16x8*)&As[wM + 16 + l16][kk + quad * 8];
            bf16x8 b0 = *(const bf16x8*)&Bs[wN + l16][kk + quad * 8];
            bf16x8 b1 = *(const bf16x8*)&Bs[wN + 16 + l16][kk + quad * 8];
            acc[0][0] = __builtin_amdgcn_mfma_f32_16x16x32_bf16(a0, b0, acc[0][0], 0, 0, 0);
            acc[0][1] = __builtin_amdgcn_mfma_f32_16x16x32_bf16(a0, b1, acc[0][1], 0, 0, 0);
            acc[1][0] = __builtin_amdgcn_mfma_f32_16x16x32_bf16(a1, b0, acc[1][0], 0, 0, 0);
            acc[1][1] = __builtin_amdgcn_mfma_f32_16x16x32_bf16(a1, b1, acc[1][1], 0, 0, 0);
        }
        __syncthreads();
    }

    // epilogue: bias + exact gelu, store bf16
#pragma unroll
    for (int mi = 0; mi < 2; ++mi) {
#pragma unroll
        for (int ni = 0; ni < 2; ++ni) {
            const int n = n0 + wN + ni * 16 + l16;
            const float bn = bias[n];
#pragma unroll
            for (int r = 0; r < 4; ++r) {
                const int m = m0 + wM + mi * 16 + quad * 4 + r;
                float v = acc[mi][ni][r] + bn;
                float g = 0.5f * v * (1.0f + erff(v * 0.70710678118654752f));
                C[(size_t)m * N + n] = f2bf(g);
            }
        }
    }
}

// ---------------------------------------------------------------------------
// Kernel 5: out[pair][n] = sigmoid(x2[pair] . W3[n] + b3[n]) * 8 + 1, masked.
// one wave per pair.
// ---------------------------------------------------------------------------
__global__ __launch_bounds__(256) void head_kernel(const unsigned short* __restrict__ x2,
                                                   const float* __restrict__ W3,
                                                   const float* __restrict__ b3,
                                                   const float* __restrict__ mask,
                                                   float* __restrict__ out) {
    const int wid = threadIdx.x >> 6;
    const int lane = threadIdx.x & 63;
    const int pair = blockIdx.x * 4 + wid;   // 1024 blocks * 4 waves = 4096

    const float v0 = bf2f(x2[(size_t)pair * 128 + lane]);
    const float v1 = bf2f(x2[(size_t)pair * 128 + 64 + lane]);
    float a0 = v0 * W3[lane] + v1 * W3[64 + lane];
    float a1 = v0 * W3[128 + lane] + v1 * W3[192 + lane];
#pragma unroll
    for (int off = 32; off; off >>= 1) {
        a0 += __shfl_down(a0, off);
        a1 += __shfl_down(a1, off);
    }
    if (lane == 0) {
        const float mk = (mask[pair] >= 0.5f) ? 1.0f : 0.0f;
        const float o0 = (1.0f / (1.0f + expf(-(a0 + b3[0])))) * 8.0f + 1.0f;
        const float o1 = (1.0f / (1.0f + expf(-(a1 + b3[1])))) * 8.0f + 1.0f;
        out[pair * 2 + 0] = o0 * mk;
        out[pair * 2 + 1] = o1 * mk;
    }
}

// ---------------------------------------------------------------------------
extern "C" void kernel_launch(void* const* d_in, const int* in_sizes, int n_in,
                              void* d_out, int out_size, void* d_ws, size_t ws_size,
                              hipStream_t stream) {
    const float* hs   = (const float*)d_in[0];
    const int*   spans= (const int*)d_in[1];
    const float* mask = (const float*)d_in[2];
    const float* W1   = (const float*)d_in[3];
    const float* b1   = (const float*)d_in[4];
    const float* W2   = (const float*)d_in[5];
    const float* b2   = (const float*)d_in[6];
    const float* W3   = (const float*)d_in[7];
    const float* b3   = (const float*)d_in[8];
    float* out = (float*)d_out;

    unsigned short* hp  = (unsigned short*)d_ws;          // 4096*3072
    unsigned short* w1b = hp  + (size_t)4096 * 3072;      // 256*3072
    unsigned short* w2b = w1b + (size_t)256 * 3072;       // 128*256
    unsigned short* x1  = w2b + (size_t)128 * 256;        // 4096*256
    unsigned short* x2  = x1  + (size_t)4096 * 256;       // 4096*128

    pool_kernel<<<dim3(4096), dim3(256), 0, stream>>>(hs, spans, hp);
    convert_w<<<dim3(512), dim3(256), 0, stream>>>(W1, W2, w1b, w2b);
    gemm_bt_gelu<<<dim3(64, 4), dim3(256), 0, stream>>>(hp, w1b, b1, x1, 4096, 256, 3072);
    gemm_bt_gelu<<<dim3(64, 2), dim3(256), 0, stream>>>(x1, w2b, b2, x2, 4096, 128, 256);
    head_kernel<<<dim3(1024), dim3(256), 0, stream>>>(x2, W3, b3, mask, out);
}

// Round 2
// 181.344 us; speedup vs baseline: 1.1293x; 1.1293x over previous
//
#include <hip/hip_runtime.h>
#include <hip/hip_bf16.h>
#include <math.h>

#define Bn 32
#define Ln 512
#define Hn 1024
#define Qn 128

typedef __bf16 bf16x8 __attribute__((ext_vector_type(8)));
typedef float f32x4 __attribute__((ext_vector_type(4)));

__device__ __forceinline__ unsigned short f2bf(float x) {
    union { float f; unsigned int u; } v; v.f = x;
    unsigned int r = v.u + 0x7fffu + ((v.u >> 16) & 1u);  // round-to-nearest-even
    return (unsigned short)(r >> 16);
}
__device__ __forceinline__ float bf2f(unsigned short h) {
    union { unsigned int u; float f; } v; v.u = ((unsigned int)h) << 16;
    return v.f;
}
__device__ __forceinline__ float gelu_exact(float v) {
    return 0.5f * v * (1.0f + erff(v * 0.70710678118654752f));
}

// ---------------------------------------------------------------------------
// Kernel 1: span pooling -> h_pair (4096 x 3072) bf16
// one block per (b,q) pair; 256 threads, 4 hidden dims each (float4)
// ---------------------------------------------------------------------------
__global__ __launch_bounds__(256) void pool_kernel(const float* __restrict__ hs,
                                                   const int* __restrict__ spans,
                                                   unsigned short* __restrict__ hp) {
    const int pair = blockIdx.x;          // b*Q + q
    const int b = pair >> 7;              // Q = 128
    const int tid = threadIdx.x;

    // dtype probe: int64 spans -> second 32-bit word is high half of asp_s[0]
    // (== 0); int32 spans -> it's asp_e[0] which is always >= 2.
    const bool is64 = (spans[1] == 0);
    int s_a, e_a, s_o, e_o;
    if (is64) {
        s_a = spans[(pair * 4 + 0) * 2]; e_a = spans[(pair * 4 + 1) * 2];
        s_o = spans[(pair * 4 + 2) * 2]; e_o = spans[(pair * 4 + 3) * 2];
    } else {
        s_a = spans[pair * 4 + 0]; e_a = spans[pair * 4 + 1];
        s_o = spans[pair * 4 + 2]; e_o = spans[pair * 4 + 3];
    }

    const float4* base = (const float4*)hs + (size_t)b * Ln * (Hn / 4);

    float4 A, O;
    if (s_a >= 2 && e_a >= s_a) {
        float sx = 0.f, sy = 0.f, sz = 0.f, sw = 0.f;
        for (int t = s_a; t <= e_a; ++t) {
            float4 v = base[t * (Hn / 4) + tid];
            sx += v.x; sy += v.y; sz += v.z; sw += v.w;
        }
        float inv = 1.0f / (float)(e_a - s_a + 1);
        A.x = sx * inv; A.y = sy * inv; A.z = sz * inv; A.w = sw * inv;
    } else {
        A = base[(Hn / 4) + tid];         // sep token, row 1
    }
    if (s_o >= 2 && e_o >= s_o) {
        float sx = 0.f, sy = 0.f, sz = 0.f, sw = 0.f;
        for (int t = s_o; t <= e_o; ++t) {
            float4 v = base[t * (Hn / 4) + tid];
            sx += v.x; sy += v.y; sz += v.z; sw += v.w;
        }
        float inv = 1.0f / (float)(e_o - s_o + 1);
        O.x = sx * inv; O.y = sy * inv; O.z = sz * inv; O.w = sw * inv;
    } else {
        O = base[(Hn / 4) + tid];
    }

    unsigned short* row = hp + (size_t)pair * 3072;
    const int d = tid * 4;
    ushort4 pa, po, pp;
    pa.x = f2bf(A.x); pa.y = f2bf(A.y); pa.z = f2bf(A.z); pa.w = f2bf(A.w);
    po.x = f2bf(O.x); po.y = f2bf(O.y); po.z = f2bf(O.z); po.w = f2bf(O.w);
    pp.x = f2bf(A.x * O.x); pp.y = f2bf(A.y * O.y);
    pp.z = f2bf(A.z * O.z); pp.w = f2bf(A.w * O.w);
    *(ushort4*)(row + d) = pa;
    *(ushort4*)(row + 1024 + d) = po;
    *(ushort4*)(row + 2048 + d) = pp;
}

// ---------------------------------------------------------------------------
// Split-K GEMM: xacc += A @ Wf^T  (fp32 atomic accumulation)
// A: M x K bf16 row-major. Wf: N x K fp32 row-major (converted to bf16 while
// staging into LDS). Tile 128x64 per block, 4 waves (2x2), each wave 64x32
// via 4x2 mfma_f32_16x16x32_bf16. grid = (M/128, N/64, S), K-chunk Ks = K/S.
// Requires Ks % 64 == 0.
// ---------------------------------------------------------------------------
__global__ __launch_bounds__(256) void gemm_splitk(const unsigned short* __restrict__ A,
                                                   const float* __restrict__ Wf,
                                                   float* __restrict__ xacc,
                                                   int M, int N, int K, int Ks) {
    __shared__ __align__(16) unsigned short As[128][72];
    __shared__ __align__(16) unsigned short Bs[64][72];

    const int tid = threadIdx.x;
    const int lane = tid & 63;
    const int wid = tid >> 6;
    const int wM = (wid >> 1) * 64;
    const int wN = (wid & 1) * 32;
    const int quad = lane >> 4;
    const int l16 = lane & 15;
    const int m0 = blockIdx.x * 128;
    const int n0 = blockIdx.y * 64;
    const int kb0 = blockIdx.z * Ks;

    f32x4 acc[4][2] = {};

    for (int k0 = kb0; k0 < kb0 + Ks; k0 += 64) {
#pragma unroll
        for (int p = 0; p < 4; ++p) {                 // A: 128 rows x 64 cols bf16
            const int v = tid + p * 256;
            const int r = v >> 3;
            const int c = (v & 7) * 8;
            *(uint4*)(&As[r][c]) = *(const uint4*)(A + (size_t)(m0 + r) * K + k0 + c);
        }
#pragma unroll
        for (int p = 0; p < 2; ++p) {                 // W: 64 rows x 64 cols fp32 -> bf16
            const int v = tid + p * 256;
            const int r = v >> 3;
            const int c = (v & 7) * 8;
            const float* src = Wf + (size_t)(n0 + r) * K + k0 + c;
            float4 f0 = *(const float4*)src;
            float4 f1 = *(const float4*)(src + 4);
            ushort4 u0, u1;
            u0.x = f2bf(f0.x); u0.y = f2bf(f0.y); u0.z = f2bf(f0.z); u0.w = f2bf(f0.w);
            u1.x = f2bf(f1.x); u1.y = f2bf(f1.y); u1.z = f2bf(f1.z); u1.w = f2bf(f1.w);
            *(ushort4*)(&Bs[r][c]) = u0;
            *(ushort4*)(&Bs[r][c + 4]) = u1;
        }
        __syncthreads();
#pragma unroll
        for (int kk = 0; kk < 64; kk += 32) {
            bf16x8 b0 = *(const bf16x8*)&Bs[wN + l16][kk + quad * 8];
            bf16x8 b1 = *(const bf16x8*)&Bs[wN + 16 + l16][kk + quad * 8];
#pragma unroll
            for (int mi = 0; mi < 4; ++mi) {
                bf16x8 a = *(const bf16x8*)&As[wM + mi * 16 + l16][kk + quad * 8];
                acc[mi][0] = __builtin_amdgcn_mfma_f32_16x16x32_bf16(a, b0, acc[mi][0], 0, 0, 0);
                acc[mi][1] = __builtin_amdgcn_mfma_f32_16x16x32_bf16(a, b1, acc[mi][1], 0, 0, 0);
            }
        }
        __syncthreads();
    }

#pragma unroll
    for (int mi = 0; mi < 4; ++mi) {
#pragma unroll
        for (int ni = 0; ni < 2; ++ni) {
            const int n = n0 + wN + ni * 16 + l16;
#pragma unroll
            for (int r = 0; r < 4; ++r) {
                const int m = m0 + wM + mi * 16 + quad * 4 + r;
                unsafeAtomicAdd(&xacc[(size_t)m * N + n], acc[mi][ni][r]);
            }
        }
    }
}

// ---------------------------------------------------------------------------
// bias + exact GELU: x1 = gelu(xacc + b) -> bf16.  N=256 cols.
// ---------------------------------------------------------------------------
__global__ __launch_bounds__(256) void gelu_bias(const float* __restrict__ xacc,
                                                 const float* __restrict__ bias,
                                                 unsigned short* __restrict__ xout,
                                                 int total4, int ncols4) {
    for (int i = blockIdx.x * blockDim.x + threadIdx.x; i < total4;
         i += gridDim.x * blockDim.x) {
        float4 v = ((const float4*)xacc)[i];
        float4 bv = ((const float4*)bias)[i & (ncols4 - 1)];
        ushort4 u;
        u.x = f2bf(gelu_exact(v.x + bv.x));
        u.y = f2bf(gelu_exact(v.y + bv.y));
        u.z = f2bf(gelu_exact(v.z + bv.z));
        u.w = f2bf(gelu_exact(v.w + bv.w));
        ((ushort4*)xout)[i] = u;
    }
}

// ---------------------------------------------------------------------------
// GELU2 + head fused: per pair, x2 = gelu(xacc2 + b2) (128 wide, fp32),
// out = sigmoid(x2 . W3^T + b3) * 8 + 1, masked. one wave per pair.
// ---------------------------------------------------------------------------
__global__ __launch_bounds__(256) void gelu2_head(const float* __restrict__ xacc2,
                                                  const float* __restrict__ b2,
                                                  const float* __restrict__ W3,
                                                  const float* __restrict__ b3,
                                                  const float* __restrict__ mask,
                                                  float* __restrict__ out) {
    const int wid = threadIdx.x >> 6;
    const int lane = threadIdx.x & 63;
    const int pair = blockIdx.x * 4 + wid;   // 1024 blocks * 4 waves = 4096

    const float g0 = gelu_exact(xacc2[(size_t)pair * 128 + lane] + b2[lane]);
    const float g1 = gelu_exact(xacc2[(size_t)pair * 128 + 64 + lane] + b2[64 + lane]);
    float a0 = g0 * W3[lane] + g1 * W3[64 + lane];
    float a1 = g0 * W3[128 + lane] + g1 * W3[192 + lane];
#pragma unroll
    for (int off = 32; off; off >>= 1) {
        a0 += __shfl_down(a0, off);
        a1 += __shfl_down(a1, off);
    }
    if (lane == 0) {
        const float mk = (mask[pair] >= 0.5f) ? 1.0f : 0.0f;
        const float o0 = (1.0f / (1.0f + expf(-(a0 + b3[0])))) * 8.0f + 1.0f;
        const float o1 = (1.0f / (1.0f + expf(-(a1 + b3[1])))) * 8.0f + 1.0f;
        out[pair * 2 + 0] = o0 * mk;
        out[pair * 2 + 1] = o1 * mk;
    }
}

// ---------------------------------------------------------------------------
extern "C" void kernel_launch(void* const* d_in, const int* in_sizes, int n_in,
                              void* d_out, int out_size, void* d_ws, size_t ws_size,
                              hipStream_t stream) {
    const float* hs   = (const float*)d_in[0];
    const int*   spans= (const int*)d_in[1];
    const float* mask = (const float*)d_in[2];
    const float* W1   = (const float*)d_in[3];
    const float* b1   = (const float*)d_in[4];
    const float* W2   = (const float*)d_in[5];
    const float* b2   = (const float*)d_in[6];
    const float* W3   = (const float*)d_in[7];
    const float* b3   = (const float*)d_in[8];
    float* out = (float*)d_out;

    // ws layout (29.4 MB): hp [0, 25165824) bf16 4096x3072;
    // xacc1 [25165824, 29360128) fp32 4096x256.
    // After gemm1, hp is dead: x1 (bf16 4096x256, 2 MB) aliases hp[0:2MB),
    // xacc2 (fp32 4096x128, 2 MB) aliases hp[2MB:4MB).
    unsigned short* hp    = (unsigned short*)d_ws;
    float*          xacc1 = (float*)((char*)d_ws + 25165824);
    unsigned short* x1    = (unsigned short*)d_ws;
    float*          xacc2 = (float*)((char*)d_ws + 2097152);

    hipMemsetAsync(xacc1, 0, (size_t)4096 * 256 * 4, stream);
    pool_kernel<<<dim3(4096), dim3(256), 0, stream>>>(hs, spans, hp);
    // GEMM1: M=4096, N=256, K=3072, split S=8 (Ks=384) -> 32*4*8 = 1024 blocks
    gemm_splitk<<<dim3(32, 4, 8), dim3(256), 0, stream>>>(hp, W1, xacc1, 4096, 256, 3072, 384);
    gelu_bias<<<dim3(512), dim3(256), 0, stream>>>(xacc1, b1, x1, 4096 * 256 / 4, 64);
    hipMemsetAsync(xacc2, 0, (size_t)4096 * 128 * 4, stream);
    // GEMM2: M=4096, N=128, K=256, split S=4 (Ks=64) -> 32*2*4 = 256 blocks
    gemm_splitk<<<dim3(32, 2, 4), dim3(256), 0, stream>>>(x1, W2, xacc2, 4096, 128, 256, 64);
    gelu2_head<<<dim3(1024), dim3(256), 0, stream>>>(xacc2, b2, W3, b3, mask, out);
}

// Round 3
// 160.262 us; speedup vs baseline: 1.2778x; 1.1315x over previous
//
#include <hip/hip_runtime.h>
#include <hip/hip_bf16.h>
#include <math.h>

#define Bn 32
#define Ln 512
#define Hn 1024
#define Qn 128

typedef __bf16 bf16x8 __attribute__((ext_vector_type(8)));
typedef float f32x4 __attribute__((ext_vector_type(4)));

__device__ __forceinline__ unsigned short f2bf(float x) {
    union { float f; unsigned int u; } v; v.f = x;
    unsigned int r = v.u + 0x7fffu + ((v.u >> 16) & 1u);  // round-to-nearest-even
    return (unsigned short)(r >> 16);
}
__device__ __forceinline__ float gelu_exact(float v) {
    return 0.5f * v * (1.0f + erff(v * 0.70710678118654752f));
}

// ---------------------------------------------------------------------------
// Kernel 1: span pooling -> h_pair (4096 x 3072) bf16
// one block per (b,q) pair; 256 threads, 4 hidden dims each (float4)
// ---------------------------------------------------------------------------
__global__ __launch_bounds__(256) void pool_kernel(const float* __restrict__ hs,
                                                   const int* __restrict__ spans,
                                                   unsigned short* __restrict__ hp) {
    const int pair = blockIdx.x;          // b*Q + q
    const int b = pair >> 7;              // Q = 128
    const int tid = threadIdx.x;

    // dtype probe: int64 spans -> second 32-bit word is high half of asp_s[0]
    // (== 0); int32 spans -> it's asp_e[0] which is always >= 2.
    const bool is64 = (spans[1] == 0);
    int s_a, e_a, s_o, e_o;
    if (is64) {
        s_a = spans[(pair * 4 + 0) * 2]; e_a = spans[(pair * 4 + 1) * 2];
        s_o = spans[(pair * 4 + 2) * 2]; e_o = spans[(pair * 4 + 3) * 2];
    } else {
        s_a = spans[pair * 4 + 0]; e_a = spans[pair * 4 + 1];
        s_o = spans[pair * 4 + 2]; e_o = spans[pair * 4 + 3];
    }

    const float4* base = (const float4*)hs + (size_t)b * Ln * (Hn / 4);

    float4 A, O;
    if (s_a >= 2 && e_a >= s_a) {
        float sx = 0.f, sy = 0.f, sz = 0.f, sw = 0.f;
        for (int t = s_a; t <= e_a; ++t) {
            float4 v = base[t * (Hn / 4) + tid];
            sx += v.x; sy += v.y; sz += v.z; sw += v.w;
        }
        float inv = 1.0f / (float)(e_a - s_a + 1);
        A.x = sx * inv; A.y = sy * inv; A.z = sz * inv; A.w = sw * inv;
    } else {
        A = base[(Hn / 4) + tid];         // sep token, row 1
    }
    if (s_o >= 2 && e_o >= s_o) {
        float sx = 0.f, sy = 0.f, sz = 0.f, sw = 0.f;
        for (int t = s_o; t <= e_o; ++t) {
            float4 v = base[t * (Hn / 4) + tid];
            sx += v.x; sy += v.y; sz += v.z; sw += v.w;
        }
        float inv = 1.0f / (float)(e_o - s_o + 1);
        O.x = sx * inv; O.y = sy * inv; O.z = sz * inv; O.w = sw * inv;
    } else {
        O = base[(Hn / 4) + tid];
    }

    unsigned short* row = hp + (size_t)pair * 3072;
    const int d = tid * 4;
    ushort4 pa, po, pp;
    pa.x = f2bf(A.x); pa.y = f2bf(A.y); pa.z = f2bf(A.z); pa.w = f2bf(A.w);
    po.x = f2bf(O.x); po.y = f2bf(O.y); po.z = f2bf(O.z); po.w = f2bf(O.w);
    pp.x = f2bf(A.x * O.x); pp.y = f2bf(A.y * O.y);
    pp.z = f2bf(A.z * O.z); pp.w = f2bf(A.w * O.w);
    *(ushort4*)(row + d) = pa;
    *(ushort4*)(row + 1024 + d) = po;
    *(ushort4*)(row + 2048 + d) = pp;
}

// ---------------------------------------------------------------------------
// GEMM1 split-K, software-pipelined double-buffer:
// xacc += A @ Wf^T. A: M x K bf16, Wf: N x K fp32 (bf16-converted at LDS
// write). 64x64 tile, 4 waves 2x2, wave 32x32 via 2x2 mfma_16x16x32_bf16.
// grid = (M/64, N/64, S), Ks = K/S, Ks % 64 == 0.
// LDS 36.9 KB -> 4 blocks/CU -> 16 waves/CU.
// ---------------------------------------------------------------------------
__global__ __launch_bounds__(256, 4) void gemm1_pipe(const unsigned short* __restrict__ A,
                                                     const float* __restrict__ Wf,
                                                     float* __restrict__ xacc,
                                                     int M, int N, int K, int Ks) {
    __shared__ __align__(16) unsigned short As[2][64][72];
    __shared__ __align__(16) unsigned short Bs[2][64][72];

    const int tid = threadIdx.x;
    const int lane = tid & 63;
    const int wid = tid >> 6;
    const int wM = (wid >> 1) * 32;
    const int wN = (wid & 1) * 32;
    const int quad = lane >> 4;
    const int l16 = lane & 15;
    const int m0 = blockIdx.x * 64;
    const int n0 = blockIdx.y * 64;
    const int kb0 = blockIdx.z * Ks;
    const int r = tid >> 3;           // 0..31
    const int c = (tid & 7) * 8;      // 0..56 step 8

    const unsigned short* Ap0 = A + (size_t)(m0 + r) * K + kb0 + c;
    const unsigned short* Ap1 = Ap0 + (size_t)32 * K;
    const float* Bp0 = Wf + (size_t)(n0 + r) * K + kb0 + c;
    const float* Bp1 = Bp0 + (size_t)32 * K;

    uint4 ra0, ra1;
    float4 rb0, rb1, rb2, rb3;

    // prologue: tile 0 -> regs -> LDS[0]
    ra0 = *(const uint4*)Ap0;
    ra1 = *(const uint4*)Ap1;
    rb0 = *(const float4*)Bp0; rb1 = *(const float4*)(Bp0 + 4);
    rb2 = *(const float4*)Bp1; rb3 = *(const float4*)(Bp1 + 4);
    {
        *(uint4*)&As[0][r][c] = ra0;
        *(uint4*)&As[0][r + 32][c] = ra1;
        ushort4 u;
        u.x = f2bf(rb0.x); u.y = f2bf(rb0.y); u.z = f2bf(rb0.z); u.w = f2bf(rb0.w);
        *(ushort4*)&Bs[0][r][c] = u;
        u.x = f2bf(rb1.x); u.y = f2bf(rb1.y); u.z = f2bf(rb1.z); u.w = f2bf(rb1.w);
        *(ushort4*)&Bs[0][r][c + 4] = u;
        u.x = f2bf(rb2.x); u.y = f2bf(rb2.y); u.z = f2bf(rb2.z); u.w = f2bf(rb2.w);
        *(ushort4*)&Bs[0][r + 32][c] = u;
        u.x = f2bf(rb3.x); u.y = f2bf(rb3.y); u.z = f2bf(rb3.z); u.w = f2bf(rb3.w);
        *(ushort4*)&Bs[0][r + 32][c + 4] = u;
    }

    f32x4 acc[2][2] = {};
    const int iters = Ks / 64;

    for (int it = 0; it < iters; ++it) {
        const int buf = it & 1;
        __syncthreads();
        if (it + 1 < iters) {             // issue next-tile loads (stay in flight
            const int off = (it + 1) * 64; // across the MFMA block below)
            ra0 = *(const uint4*)(Ap0 + off);
            ra1 = *(const uint4*)(Ap1 + off);
            rb0 = *(const float4*)(Bp0 + off); rb1 = *(const float4*)(Bp0 + off + 4);
            rb2 = *(const float4*)(Bp1 + off); rb3 = *(const float4*)(Bp1 + off + 4);
        }
#pragma unroll
        for (int kk = 0; kk < 64; kk += 32) {
            bf16x8 a0 = *(const bf16x8*)&As[buf][wM + l16][kk + quad * 8];
            bf16x8 a1 = *(const bf16x8*)&As[buf][wM + 16 + l16][kk + quad * 8];
            bf16x8 b0 = *(const bf16x8*)&Bs[buf][wN + l16][kk + quad * 8];
            bf16x8 b1 = *(const bf16x8*)&Bs[buf][wN + 16 + l16][kk + quad * 8];
            acc[0][0] = __builtin_amdgcn_mfma_f32_16x16x32_bf16(a0, b0, acc[0][0], 0, 0, 0);
            acc[0][1] = __builtin_amdgcn_mfma_f32_16x16x32_bf16(a0, b1, acc[0][1], 0, 0, 0);
            acc[1][0] = __builtin_amdgcn_mfma_f32_16x16x32_bf16(a1, b0, acc[1][0], 0, 0, 0);
            acc[1][1] = __builtin_amdgcn_mfma_f32_16x16x32_bf16(a1, b1, acc[1][1], 0, 0, 0);
        }
        if (it + 1 < iters) {             // regs -> other LDS buffer
            const int nb = buf ^ 1;
            *(uint4*)&As[nb][r][c] = ra0;
            *(uint4*)&As[nb][r + 32][c] = ra1;
            ushort4 u;
            u.x = f2bf(rb0.x); u.y = f2bf(rb0.y); u.z = f2bf(rb0.z); u.w = f2bf(rb0.w);
            *(ushort4*)&Bs[nb][r][c] = u;
            u.x = f2bf(rb1.x); u.y = f2bf(rb1.y); u.z = f2bf(rb1.z); u.w = f2bf(rb1.w);
            *(ushort4*)&Bs[nb][r][c + 4] = u;
            u.x = f2bf(rb2.x); u.y = f2bf(rb2.y); u.z = f2bf(rb2.z); u.w = f2bf(rb2.w);
            *(ushort4*)&Bs[nb][r + 32][c] = u;
            u.x = f2bf(rb3.x); u.y = f2bf(rb3.y); u.z = f2bf(rb3.z); u.w = f2bf(rb3.w);
            *(ushort4*)&Bs[nb][r + 32][c + 4] = u;
        }
    }

#pragma unroll
    for (int mi = 0; mi < 2; ++mi) {
#pragma unroll
        for (int ni = 0; ni < 2; ++ni) {
            const int n = n0 + wN + ni * 16 + l16;
#pragma unroll
            for (int rr = 0; rr < 4; ++rr) {
                const int m = m0 + wM + mi * 16 + quad * 4 + rr;
                unsafeAtomicAdd(&xacc[(size_t)m * N + n], acc[mi][ni][rr]);
            }
        }
    }
}

// ---------------------------------------------------------------------------
// bias + exact GELU: x1 = gelu(xacc + b) -> bf16.  ncols4 = N/4 (pow2).
// ---------------------------------------------------------------------------
__global__ __launch_bounds__(256) void gelu_bias(const float* __restrict__ xacc,
                                                 const float* __restrict__ bias,
                                                 unsigned short* __restrict__ xout,
                                                 int total4, int ncols4) {
    for (int i = blockIdx.x * blockDim.x + threadIdx.x; i < total4;
         i += gridDim.x * blockDim.x) {
        float4 v = ((const float4*)xacc)[i];
        float4 bv = ((const float4*)bias)[i & (ncols4 - 1)];
        ushort4 u;
        u.x = f2bf(gelu_exact(v.x + bv.x));
        u.y = f2bf(gelu_exact(v.y + bv.y));
        u.z = f2bf(gelu_exact(v.z + bv.z));
        u.w = f2bf(gelu_exact(v.w + bv.w));
        ((ushort4*)xout)[i] = u;
    }
}

// ---------------------------------------------------------------------------
// Fused GEMM2 + bias + GELU + head:
// per block: 32 pairs. x2 = gelu(x1 @ W2^T + b2) (32 x 128, MFMA),
// out = sigmoid(x2 . W3^T + b3) * 8 + 1, masked. grid = 128 blocks.
// ---------------------------------------------------------------------------
__global__ __launch_bounds__(256) void mlp2_head(const unsigned short* __restrict__ x1,
                                                 const float* __restrict__ W2f,
                                                 const float* __restrict__ b2,
                                                 const float* __restrict__ W3,
                                                 const float* __restrict__ b3,
                                                 const float* __restrict__ mask,
                                                 float* __restrict__ out) {
    __shared__ __align__(16) unsigned short Xs[32][72];
    __shared__ __align__(16) unsigned short Ws[128][72];
    __shared__ float X2[32][132];

    const int tid = threadIdx.x;
    const int lane = tid & 63;
    const int wid = tid >> 6;
    const int wM = (wid >> 1) * 16;   // waves 2x2: wave tile 16 x 64
    const int wN = (wid & 1) * 64;
    const int quad = lane >> 4;
    const int l16 = lane & 15;
    const int m0 = blockIdx.x * 32;

    f32x4 acc[4] = {};

    for (int k0 = 0; k0 < 256; k0 += 64) {
        {   // stage Xs 32x64 bf16: one 16B chunk per thread
            const int r = tid >> 3, c = (tid & 7) * 8;
            *(uint4*)&Xs[r][c] = *(const uint4*)(x1 + (size_t)(m0 + r) * 256 + k0 + c);
        }
#pragma unroll
        for (int p = 0; p < 4; ++p) {   // stage Ws 128x64 from fp32
            const int v = tid + p * 256;
            const int r = v >> 3, c = (v & 7) * 8;
            const float* src = W2f + (size_t)r * 256 + k0 + c;
            float4 f0 = *(const float4*)src;
            float4 f1 = *(const float4*)(src + 4);
            ushort4 u;
            u.x = f2bf(f0.x); u.y = f2bf(f0.y); u.z = f2bf(f0.z); u.w = f2bf(f0.w);
            *(ushort4*)&Ws[r][c] = u;
            u.x = f2bf(f1.x); u.y = f2bf(f1.y); u.z = f2bf(f1.z); u.w = f2bf(f1.w);
            *(ushort4*)&Ws[r][c + 4] = u;
        }
        __syncthreads();
#pragma unroll
        for (int kk = 0; kk < 64; kk += 32) {
            bf16x8 a = *(const bf16x8*)&Xs[wM + l16][kk + quad * 8];
#pragma unroll
            for (int ni = 0; ni < 4; ++ni) {
                bf16x8 b = *(const bf16x8*)&Ws[wN + ni * 16 + l16][kk + quad * 8];
                acc[ni] = __builtin_amdgcn_mfma_f32_16x16x32_bf16(a, b, acc[ni], 0, 0, 0);
            }
        }
        __syncthreads();
    }

    // bias + gelu -> X2 (fp32 LDS)
#pragma unroll
    for (int ni = 0; ni < 4; ++ni) {
        const int n = wN + ni * 16 + l16;
        const float bn = b2[n];
#pragma unroll
        for (int rr = 0; rr < 4; ++rr) {
            const int m = wM + quad * 4 + rr;
            X2[m][n] = gelu_exact(acc[ni][rr] + bn);
        }
    }
    __syncthreads();

    // head: 8 threads per pair, each 16 cols
    const int p = tid >> 3;           // 0..31
    const int cc = (tid & 7) * 16;    // 0..112
    float a0 = 0.f, a1 = 0.f;
#pragma unroll
    for (int j = 0; j < 16; ++j) {
        const float xv = X2[p][cc + j];
        a0 += xv * W3[cc + j];
        a1 += xv * W3[128 + cc + j];
    }
    a0 += __shfl_xor(a0, 1); a0 += __shfl_xor(a0, 2); a0 += __shfl_xor(a0, 4);
    a1 += __shfl_xor(a1, 1); a1 += __shfl_xor(a1, 2); a1 += __shfl_xor(a1, 4);
    if ((tid & 7) == 0) {
        const int pair = m0 + p;
        const float mk = (mask[pair] >= 0.5f) ? 1.0f : 0.0f;
        out[pair * 2 + 0] = ((1.0f / (1.0f + expf(-(a0 + b3[0])))) * 8.0f + 1.0f) * mk;
        out[pair * 2 + 1] = ((1.0f / (1.0f + expf(-(a1 + b3[1])))) * 8.0f + 1.0f) * mk;
    }
}

// ---------------------------------------------------------------------------
extern "C" void kernel_launch(void* const* d_in, const int* in_sizes, int n_in,
                              void* d_out, int out_size, void* d_ws, size_t ws_size,
                              hipStream_t stream) {
    const float* hs   = (const float*)d_in[0];
    const int*   spans= (const int*)d_in[1];
    const float* mask = (const float*)d_in[2];
    const float* W1   = (const float*)d_in[3];
    const float* b1   = (const float*)d_in[4];
    const float* W2   = (const float*)d_in[5];
    const float* b2   = (const float*)d_in[6];
    const float* W3   = (const float*)d_in[7];
    const float* b3   = (const float*)d_in[8];
    float* out = (float*)d_out;

    // ws (29.36 MB, same footprint as validated round 2):
    // hp bf16 4096x3072 [0, 25165824); xacc1 fp32 4096x256 [25165824, 29360128).
    // x1 (bf16 4096x256, 2 MB) aliases hp[0:2MB) once gemm1 is done.
    unsigned short* hp    = (unsigned short*)d_ws;
    float*          xacc1 = (float*)((char*)d_ws + 25165824);
    unsigned short* x1    = (unsigned short*)d_ws;

    hipMemsetAsync(xacc1, 0, (size_t)4096 * 256 * 4, stream);
    pool_kernel<<<dim3(4096), dim3(256), 0, stream>>>(hs, spans, hp);
    // GEMM1: M=4096, N=256, K=3072, S=4 (Ks=768) -> 64*4*4 = 1024 blocks, 4/CU
    gemm1_pipe<<<dim3(64, 4, 4), dim3(256), 0, stream>>>(hp, W1, xacc1, 4096, 256, 3072, 768);
    gelu_bias<<<dim3(512), dim3(256), 0, stream>>>(xacc1, b1, x1, 4096 * 256 / 4, 64);
    mlp2_head<<<dim3(128), dim3(256), 0, stream>>>(x1, W2, b2, W3, b3, mask, out);
}